// Round 1
// baseline (116.305 us; speedup 1.0000x reference)
//
#include <hip/hip_runtime.h>

// GLIF3 neuron update, B = 8388608 neurons, M = 2 ascending currents.
// Elementwise, memory-bound: 56 B read + 16 B write per neuron = 604 MB total.
// 1 thread = 4 neurons, float4 everywhere (fully coalesced).
//
// Numerics: match numpy f32 as closely as possible so the hard spike
// threshold (v_prime > v_th) doesn't flip: precise expf, IEEE div,
// fp contract off (per-op rounding like numpy).

static constexpr int B_N = 8388608;

__global__ __launch_bounds__(256) void glif3_kernel(
    const float4* __restrict__ v_in,
    const float4* __restrict__ iasc_in,   // (B,2) -> 2 float4 per thread
    const float4* __restrict__ x_in,
    const float4* __restrict__ vth_in,
    const float4* __restrict__ vreset_in,
    const float4* __restrict__ vrest_in,
    const float4* __restrict__ cm_in,
    const float4* __restrict__ tau_in,
    const float4* __restrict__ k_in,      // (B,2)
    const float4* __restrict__ amps_in,   // (B,2)
    const float4* __restrict__ nref_in,
    float4* __restrict__ vpost_out,
    float4* __restrict__ ipost_out,       // (B,2)
    float4* __restrict__ s_out,
    int n4)
{
#pragma clang fp contract(off)
    int i = blockIdx.x * blockDim.x + threadIdx.x;
    if (i >= n4) return;

    float4 v4   = v_in[i];
    float4 x4   = x_in[i];
    float4 th4  = vth_in[i];
    float4 rs4  = vreset_in[i];
    float4 re4  = vrest_in[i];
    float4 cm4  = cm_in[i];
    float4 tau4 = tau_in[i];
    float4 nr4  = nref_in[i];
    float4 ia0  = iasc_in[2 * i];
    float4 ia1  = iasc_in[2 * i + 1];
    float4 k0   = k_in[2 * i];
    float4 k1   = k_in[2 * i + 1];
    float4 am0  = amps_in[2 * i];
    float4 am1  = amps_in[2 * i + 1];

    float vA[4]   = {v4.x, v4.y, v4.z, v4.w};
    float xA[4]   = {x4.x, x4.y, x4.z, x4.w};
    float thA[4]  = {th4.x, th4.y, th4.z, th4.w};
    float rsA[4]  = {rs4.x, rs4.y, rs4.z, rs4.w};
    float reA[4]  = {re4.x, re4.y, re4.z, re4.w};
    float cmA[4]  = {cm4.x, cm4.y, cm4.z, cm4.w};
    float tauA[4] = {tau4.x, tau4.y, tau4.z, tau4.w};
    float nrA[4]  = {nr4.x, nr4.y, nr4.z, nr4.w};
    float iaA[8]  = {ia0.x, ia0.y, ia0.z, ia0.w, ia1.x, ia1.y, ia1.z, ia1.w};
    float kA[8]   = {k0.x, k0.y, k0.z, k0.w, k1.x, k1.y, k1.z, k1.w};
    float amA[8]  = {am0.x, am0.y, am0.z, am0.w, am1.x, am1.y, am1.z, am1.w};

    float vpA[4], sA[4], ipA[8];

#pragma unroll
    for (int j = 0; j < 4; ++j) {
        // a = exp(-DT/tau), DT = 1
        float a = expf(-1.0f / tauA[j]);
        float isum = iaA[2 * j] + iaA[2 * j + 1];
        // v_inf = v_rest + tau*(x+I_sum)/c_m   (python eval order: ((tau*(x+I)) / c_m) + v_rest)
        float v_inf = reA[j] + (tauA[j] * (xA[j] + isum)) / cmA[j];
        float v_prime = v_inf + (vA[j] - v_inf) * a;
        // s = ((v_prime - v_th) > 0) * not_refrac ; (a-b)>0 <=> a>b in IEEE
        float s = (v_prime > thA[j]) ? nrA[j] : 0.0f;
        // soft reset (HARD_RESET = False)
        vpA[j] = v_prime - (thA[j] - rsA[j]) * s;
        sA[j] = s;
        ipA[2 * j]     = iaA[2 * j]     * expf(-kA[2 * j])     + amA[2 * j]     * s;
        ipA[2 * j + 1] = iaA[2 * j + 1] * expf(-kA[2 * j + 1]) + amA[2 * j + 1] * s;
    }

    vpost_out[i]        = make_float4(vpA[0], vpA[1], vpA[2], vpA[3]);
    ipost_out[2 * i]     = make_float4(ipA[0], ipA[1], ipA[2], ipA[3]);
    ipost_out[2 * i + 1] = make_float4(ipA[4], ipA[5], ipA[6], ipA[7]);
    s_out[i]            = make_float4(sA[0], sA[1], sA[2], sA[3]);
}

extern "C" void kernel_launch(void* const* d_in, const int* in_sizes, int n_in,
                              void* d_out, int out_size, void* d_ws, size_t ws_size,
                              hipStream_t stream) {
    // setup_inputs order:
    // 0: v (B), 1: Iasc (B,2), 2: x (B), 3: v_th (B), 4: v_reset (B),
    // 5: v_rest (B), 6: c_m (B), 7: tau (B), 8: k (B,2), 9: asc_amps (B,2),
    // 10: not_refrac (B)
    const float4* v     = (const float4*)d_in[0];
    const float4* iasc  = (const float4*)d_in[1];
    const float4* x     = (const float4*)d_in[2];
    const float4* vth   = (const float4*)d_in[3];
    const float4* vrst  = (const float4*)d_in[4];
    const float4* vrest = (const float4*)d_in[5];
    const float4* cm    = (const float4*)d_in[6];
    const float4* tau   = (const float4*)d_in[7];
    const float4* k     = (const float4*)d_in[8];
    const float4* amps  = (const float4*)d_in[9];
    const float4* nref  = (const float4*)d_in[10];

    const int B = in_sizes[0];            // 8388608
    float* out = (float*)d_out;
    float4* vpost = (float4*)out;                       // [0, B)
    float4* ipost = (float4*)(out + (size_t)B);         // [B, 3B)
    float4* sout  = (float4*)(out + (size_t)3 * B);     // [3B, 4B)

    const int n4 = B / 4;                 // 2097152 threads
    const int block = 256;
    const int grid = (n4 + block - 1) / block;  // 8192

    glif3_kernel<<<grid, block, 0, stream>>>(v, iasc, x, vth, vrst, vrest, cm,
                                             tau, k, amps, nref,
                                             vpost, ipost, sout, n4);
}

// Round 2
// 116.004 us; speedup vs baseline: 1.0026x; 1.0026x over previous
//
#include <hip/hip_runtime.h>

// GLIF3 neuron update, B = 8388608, M = 2. Memory-bound streaming kernel.
// Round 2: 8 neurons/thread (2 coalesced float4 chunks per stream), ALL loads
// issued before any compute (sched_barrier(0) fence) to maximize per-wave MLP.
// Round-1 failure mode: compiler throttled to 32 VGPRs and serialized loads
// -> latency-bound at 3.1 TB/s effective.
//
// Numerics: precise expf, IEEE div, fp contract off -> matches numpy f32
// per-op rounding so the hard spike threshold doesn't flip.

__device__ __forceinline__ void glif1(float v, float x, float th, float rs,
                                      float re, float cm, float tau, float nr,
                                      float ia0, float ia1, float k0, float k1,
                                      float am0, float am1,
                                      float& vp, float& ip0, float& ip1, float& s)
{
#pragma clang fp contract(off)
    float a = expf(-1.0f / tau);                    // DT = 1
    float isum = ia0 + ia1;
    float v_inf = re + (tau * (x + isum)) / cm;     // python eval order
    float v_prime = v_inf + (v - v_inf) * a;
    s = (v_prime > th) ? nr : 0.0f;                 // (a-b)>0 <=> a>b in IEEE
    vp = v_prime - (th - rs) * s;                   // soft reset
    ip0 = ia0 * expf(-k0) + am0 * s;
    ip1 = ia1 * expf(-k1) + am1 * s;
}

__device__ __forceinline__ void compute4(
    float4 v, float4 x, float4 th, float4 rs, float4 re, float4 cm,
    float4 tau, float4 nr, float4 ia0, float4 ia1, float4 k0, float4 k1,
    float4 am0, float4 am1,
    float4& vp, float4& ipA, float4& ipB, float4& s)
{
    // neuron j uses interleaved (B,2) elements: ia0 = elems 0..3 = neurons 0,0',1,1'
    // ia0 = {n0m0, n0m1, n1m0, n1m1}, ia1 = {n2m0, n2m1, n3m0, n3m1}
    glif1(v.x, x.x, th.x, rs.x, re.x, cm.x, tau.x, nr.x,
          ia0.x, ia0.y, k0.x, k0.y, am0.x, am0.y, vp.x, ipA.x, ipA.y, s.x);
    glif1(v.y, x.y, th.y, rs.y, re.y, cm.y, tau.y, nr.y,
          ia0.z, ia0.w, k0.z, k0.w, am0.z, am0.w, vp.y, ipA.z, ipA.w, s.y);
    glif1(v.z, x.z, th.z, rs.z, re.z, cm.z, tau.z, nr.z,
          ia1.x, ia1.y, k1.x, k1.y, am1.x, am1.y, vp.z, ipB.x, ipB.y, s.z);
    glif1(v.w, x.w, th.w, rs.w, re.w, cm.w, tau.w, nr.w,
          ia1.z, ia1.w, k1.z, k1.w, am1.z, am1.w, vp.w, ipB.z, ipB.w, s.w);
}

__global__ __launch_bounds__(256) void glif3_kernel(
    const float4* __restrict__ v_in,
    const float4* __restrict__ iasc_in,
    const float4* __restrict__ x_in,
    const float4* __restrict__ vth_in,
    const float4* __restrict__ vreset_in,
    const float4* __restrict__ vrest_in,
    const float4* __restrict__ cm_in,
    const float4* __restrict__ tau_in,
    const float4* __restrict__ k_in,
    const float4* __restrict__ amps_in,
    const float4* __restrict__ nref_in,
    float4* __restrict__ vpost_out,
    float4* __restrict__ ipost_out,
    float4* __restrict__ s_out,
    int n4)
{
    int t = threadIdx.x;
    int e0 = blockIdx.x * 512 + t;      // chunk A (float4 index into B/4 space)
    int e1 = e0 + 256;                  // chunk B
    if (e1 >= n4) { if (e0 >= n4) return; e1 = e0; } // never taken for B=8.4M

    // ---- issue ALL 28 loads before any use ----
    float4 Av  = v_in[e0],        Bv  = v_in[e1];
    float4 Ax  = x_in[e0],        Bx  = x_in[e1];
    float4 Ath = vth_in[e0],      Bth = vth_in[e1];
    float4 Ars = vreset_in[e0],   Brs = vreset_in[e1];
    float4 Are = vrest_in[e0],    Bre = vrest_in[e1];
    float4 Acm = cm_in[e0],       Bcm = cm_in[e1];
    float4 Atu = tau_in[e0],      Btu = tau_in[e1];
    float4 Anr = nref_in[e0],     Bnr = nref_in[e1];
    float4 Aia0 = iasc_in[2 * e0],     Aia1 = iasc_in[2 * e0 + 1];
    float4 Bia0 = iasc_in[2 * e1],     Bia1 = iasc_in[2 * e1 + 1];
    float4 Ak0  = k_in[2 * e0],        Ak1  = k_in[2 * e0 + 1];
    float4 Bk0  = k_in[2 * e1],        Bk1  = k_in[2 * e1 + 1];
    float4 Aam0 = amps_in[2 * e0],     Aam1 = amps_in[2 * e0 + 1];
    float4 Bam0 = amps_in[2 * e1],     Bam1 = amps_in[2 * e1 + 1];

    __builtin_amdgcn_sched_barrier(0);  // keep loads above, compute below

    float4 vp, ipA, ipB, s;

    compute4(Av, Ax, Ath, Ars, Are, Acm, Atu, Anr,
             Aia0, Aia1, Ak0, Ak1, Aam0, Aam1, vp, ipA, ipB, s);
    vpost_out[e0]        = vp;
    ipost_out[2 * e0]    = ipA;
    ipost_out[2 * e0 + 1] = ipB;
    s_out[e0]            = s;

    compute4(Bv, Bx, Bth, Brs, Bre, Bcm, Btu, Bnr,
             Bia0, Bia1, Bk0, Bk1, Bam0, Bam1, vp, ipA, ipB, s);
    vpost_out[e1]        = vp;
    ipost_out[2 * e1]    = ipA;
    ipost_out[2 * e1 + 1] = ipB;
    s_out[e1]            = s;
}

extern "C" void kernel_launch(void* const* d_in, const int* in_sizes, int n_in,
                              void* d_out, int out_size, void* d_ws, size_t ws_size,
                              hipStream_t stream) {
    const float4* v     = (const float4*)d_in[0];
    const float4* iasc  = (const float4*)d_in[1];
    const float4* x     = (const float4*)d_in[2];
    const float4* vth   = (const float4*)d_in[3];
    const float4* vrst  = (const float4*)d_in[4];
    const float4* vrest = (const float4*)d_in[5];
    const float4* cm    = (const float4*)d_in[6];
    const float4* tau   = (const float4*)d_in[7];
    const float4* k     = (const float4*)d_in[8];
    const float4* amps  = (const float4*)d_in[9];
    const float4* nref  = (const float4*)d_in[10];

    const int B = in_sizes[0];            // 8388608
    float* out = (float*)d_out;
    float4* vpost = (float4*)out;                       // [0, B)
    float4* ipost = (float4*)(out + (size_t)B);         // [B, 3B)
    float4* sout  = (float4*)(out + (size_t)3 * B);     // [3B, 4B)

    const int n4 = B / 4;                               // 2097152
    const int block = 256;
    const int grid = n4 / (2 * block);                  // 4096 (exact)

    glif3_kernel<<<grid, block, 0, stream>>>(v, iasc, x, vth, vrst, vrest, cm,
                                             tau, k, amps, nref,
                                             vpost, ipost, sout, n4);
}